// Round 10
// baseline (508.993 us; speedup 1.0000x reference)
//
#include <hip/hip_runtime.h>
#include <hip/hip_bf16.h>

#define BATCH 1024
#define N_STEPS 3
#define GAMMA_C 1.3f
#define BN_EPS_C 1e-5f
#define SQRT_HALF_C 0.70710678118654752440f
#define ST_STRIDE 786432   // 3*1024*256 per state array

// ---- input loader: f32 or bf16 decided at runtime by detector flag --------
__device__ __forceinline__ float ldin(const void* p, size_t i, int isbf){
  if (isbf) return __bfloat162float(((const __hip_bfloat16*)p)[i]);
  return ((const float*)p)[i];
}
__device__ __forceinline__ float4 ld4(const void* p, size_t i, int isbf){
  if (!isbf) return *(const float4*)((const float*)p + i);
  const __hip_bfloat16* q = (const __hip_bfloat16*)p + i;
  return make_float4(__bfloat162float(q[0]), __bfloat162float(q[1]),
                     __bfloat162float(q[2]), __bfloat162float(q[3]));
}

// ---- wave (64-lane) butterfly reductions ----------------------------------
__device__ __forceinline__ float wsum(float v){
#pragma unroll
  for (int o = 32; o > 0; o >>= 1) v += __shfl_xor(v, o);
  return v;
}
__device__ __forceinline__ float wmaxr(float v){
#pragma unroll
  for (int o = 32; o > 0; o >>= 1) v = fmaxf(v, __shfl_xor(v, o));
  return v;
}
__device__ __forceinline__ float wminr(float v){
#pragma unroll
  for (int o = 32; o > 0; o >>= 1) v = fminf(v, __shfl_xor(v, o));
  return v;
}
__device__ __forceinline__ float block_sum(float v, float* sb){
  int t = threadIdx.x;
  sb[t] = v; __syncthreads();
#pragma unroll
  for (int s = 128; s > 0; s >>= 1){
    if (t < s) sb[t] += sb[t + s];
    __syncthreads();
  }
  float r = sb[0]; __syncthreads();
  return r;
}

// ---- amap drain: one block writes one (step, batch-row) amap tile ---------
// state layout: q | k | m | rz, each ST_STRIDE floats, indexed (s*1024+b)*256+i
// Store phasing: amap rows start at byte ≡ 4 (mod 16), so aligned 8B float2
// stores must cover col pairs (1,2),(3,4)..(253,254); cols 0 and 255 are
// dword stores handled by the i==127 lane of each half.
__device__ __forceinline__ void drain_rows(const float* __restrict__ st,
                                           float* __restrict__ amap,
                                           int s, int b, int t){
  __shared__ __align__(16) float sh[768];
  size_t sb = ((size_t)s*BATCH + b)*256;
  sh[t]       = st[sb + t];                  // q
  sh[256 + t] = st[2*ST_STRIDE + sb + t];    // m
  sh[512 + t] = st[3*ST_STRIDE + sb + t];    // rz
  __syncthreads();
  const float* kS = st + ST_STRIDE + sb;
  int i = t & 127, rh = (t >> 7) * 128;
  size_t tile = ((size_t)s*BATCH + b)*65536;
  if (i < 127){
    int c0 = 1 + 2*i;
    float k0 = kS[c0], k1 = kS[c0 + 1];
    float* ap = amap + tile + c0;
#pragma unroll 8
    for (int r0 = 0; r0 < 128; r0 += 4){
      int r = rh + r0;
      float4 q4 = *(const float4*)&sh[r];
      float4 m4 = *(const float4*)&sh[256 + r];
      float4 s4 = *(const float4*)&sh[512 + r];
      float e00 = __expf(q4.x*k0 - m4.x) * s4.x, e01 = __expf(q4.x*k1 - m4.x) * s4.x;
      float e10 = __expf(q4.y*k0 - m4.y) * s4.y, e11 = __expf(q4.y*k1 - m4.y) * s4.y;
      float e20 = __expf(q4.z*k0 - m4.z) * s4.z, e21 = __expf(q4.z*k1 - m4.z) * s4.z;
      float e30 = __expf(q4.w*k0 - m4.w) * s4.w, e31 = __expf(q4.w*k1 - m4.w) * s4.w;
      *(float2*)(ap + (size_t)(r+0)*256) = make_float2(e00, e01);
      *(float2*)(ap + (size_t)(r+1)*256) = make_float2(e10, e11);
      *(float2*)(ap + (size_t)(r+2)*256) = make_float2(e20, e21);
      *(float2*)(ap + (size_t)(r+3)*256) = make_float2(e30, e31);
    }
  } else {
    float k0 = kS[0], k255 = kS[255];
    float* a0 = amap + tile;
    float* a255 = amap + tile + 255;
#pragma unroll 8
    for (int r0 = 0; r0 < 128; r0 += 4){
      int r = rh + r0;
      float4 q4 = *(const float4*)&sh[r];
      float4 m4 = *(const float4*)&sh[256 + r];
      float4 s4 = *(const float4*)&sh[512 + r];
      a0[(size_t)(r+0)*256]   = __expf(q4.x*k0 - m4.x) * s4.x;
      a0[(size_t)(r+1)*256]   = __expf(q4.y*k0 - m4.y) * s4.y;
      a0[(size_t)(r+2)*256]   = __expf(q4.z*k0 - m4.z) * s4.z;
      a0[(size_t)(r+3)*256]   = __expf(q4.w*k0 - m4.w) * s4.w;
      a255[(size_t)(r+0)*256] = __expf(q4.x*k255 - m4.x) * s4.x;
      a255[(size_t)(r+1)*256] = __expf(q4.y*k255 - m4.y) * s4.y;
      a255[(size_t)(r+2)*256] = __expf(q4.z*k255 - m4.z) * s4.z;
      a255[(size_t)(r+3)*256] = __expf(q4.w*k255 - m4.w) * s4.w;
    }
  }
}

// ---- dtype detector --------------------------------------------------------
__global__ void detect_k(const unsigned short* __restrict__ u, float* __restrict__ flag){
  __shared__ int cnt;
  if (threadIdx.x == 0) cnt = 0;
  __syncthreads();
  int c = 0;
  for (int j = 0; j < 16; ++j){
    unsigned short v = u[(size_t)(threadIdx.x * 16 + j) * 2];
    int e = (v >> 7) & 0xFF;
    if (e >= 118 && e <= 134) c++;
  }
  atomicAdd(&cnt, c);
  __syncthreads();
  if (threadIdx.x == 0) flag[0] = (cnt > 2048) ? 1.0f : 0.0f;
}

// ---- full-batch BN stats ---------------------------------------------------
__global__ void bnstats_k(const void* __restrict__ x, float* __restrict__ mean,
                          float* __restrict__ istd, const float* __restrict__ flg){
  __shared__ float sb[256];
  const int isbf = flg[0] != 0.0f;
  int f = blockIdx.x, t = threadIdx.x;
  float s = 0.f, ss = 0.f;
  for (int r = t; r < BATCH; r += 256){
    float v = ldin(x, (size_t)r * 256 + f, isbf);
    s += v; ss += v * v;
  }
  s  = block_sum(s, sb);
  ss = block_sum(ss, sb);
  if (t == 0){
    float m = s * (1.f / BATCH);
    mean[f] = m;
    istd[f] = rsqrtf(ss * (1.f / BATCH) - m * m + BN_EPS_C);
  }
}

__global__ void xn_k(const void* __restrict__ x, const float* __restrict__ mean,
                     const float* __restrict__ istd, const void* __restrict__ bw,
                     const void* __restrict__ bb, float* __restrict__ xn,
                     const float* __restrict__ flg){
  const int isbf = flg[0] != 0.0f;
  int idx = blockIdx.x * 256 + threadIdx.x;
  int f = idx & 255;
  xn[idx] = (ldin(x, idx, isbf) - mean[f]) * istd[f] * ldin(bw, f, isbf) + ldin(bb, f, isbf);
}

// ---- GEMM (BT): C(1024x256) = [A1|A2](1024xK) @ W^T, 1D grid, +drain ------
__global__ __launch_bounds__(256)
void gemm_bt_k(const float* __restrict__ A1, const void* __restrict__ A2, int split,
               const void* __restrict__ W, size_t woff, float* __restrict__ C, int K,
               const float* __restrict__ st, float* __restrict__ amap, int dS, int dR0,
               const float* __restrict__ flg){
  int bid = blockIdx.x, t = threadIdx.x;
  if (bid >= 256){ drain_rows(st, amap, dS, dR0 + bid - 256, t); return; }
  __shared__ float As[32][34];
  __shared__ float Ws[32][34];
  const int isbf = flg[0] != 0.0f;
  const int n0 = (bid & 7) * 32, m0 = (bid >> 3) * 32;
  const int tx = t & 15, ty = t >> 4;
  const int lr = t >> 3, lk = (t & 7) * 4;
  const int nc = K >> 5;
  float a00 = 0.f, a01 = 0.f, a10 = 0.f, a11 = 0.f;

  auto lda = [&](int k0) -> float4 {
    int gk = k0 + lk, gr = m0 + lr;
    if (gk < split) return *(const float4*)(A1 + (size_t)gr * split + gk);
    return ld4(A2, (size_t)gr * (K - split) + (gk - split), isbf);
  };
  auto ldw = [&](int k0) -> float4 {
    return ld4(W, woff + (size_t)(n0 + lr) * K + k0 + lk, isbf);
  };

  float4 ra = lda(0), rw = ldw(0);
  for (int c = 0; c < nc; ++c){
    As[lk+0][lr] = ra.x; As[lk+1][lr] = ra.y; As[lk+2][lr] = ra.z; As[lk+3][lr] = ra.w;
    Ws[lk+0][lr] = rw.x; Ws[lk+1][lr] = rw.y; Ws[lk+2][lr] = rw.z; Ws[lk+3][lr] = rw.w;
    __syncthreads();
    float4 na = ra, nw = rw;
    if (c + 1 < nc){ na = lda((c+1) << 5); nw = ldw((c+1) << 5); }
#pragma unroll
    for (int kk = 0; kk < 32; ++kk){
      float2 av = *(const float2*)&As[kk][ty*2];
      float2 wv = *(const float2*)&Ws[kk][tx*2];
      a00 += av.x * wv.x; a01 += av.x * wv.y;
      a10 += av.y * wv.x; a11 += av.y * wv.y;
    }
    __syncthreads();
    ra = na; rw = nw;
  }
  int r0 = m0 + ty*2, c0 = n0 + tx*2;
  float* Cp = C + (size_t)r0 * 256 + c0;
  Cp[0] = a00; Cp[1] = a01; Cp[256] = a10; Cp[257] = a11;
}

// ---- merged group-stats + GLU-fused GEMM K=128 -> H2, +drain --------------
__global__ __launch_bounds__(256)
void glugemm_k(const float* __restrict__ H1, const void* __restrict__ gw,
               const void* __restrict__ gb, size_t goff,
               const void* __restrict__ W, size_t woff, float* __restrict__ C,
               const float* __restrict__ st, float* __restrict__ amap, int dS, int dR0,
               const float* __restrict__ flg){
  int bid = blockIdx.x, t = threadIdx.x;
  if (bid >= 256){ drain_rows(st, amap, dS, dR0 + bid - 256, t); return; }
  __shared__ __align__(16) float sA[256], sB[256];
  __shared__ float As[32][34];
  __shared__ float Ws[32][34];
  const int isbf = flg[0] != 0.0f;
  const int n0 = (bid & 7) * 32, m0 = (bid >> 3) * 32;
  const int g = bid >> 5;
  {
    const float* Hp = H1 + (size_t)g*32768 + t;
    float s = 0.f, ss = 0.f;
#pragma unroll 8
    for (int i = 0; i < 128; ++i){ float v = Hp[(size_t)i*256]; s += v; ss += v*v; }
    float m = s * (1.f/128), is = rsqrtf(ss * (1.f/128) - m*m + BN_EPS_C);
    float wv = ldin(gw, goff + t, isbf), bv = ldin(gb, goff + t, isbf);
    float A = is * wv;
    sA[t] = A; sB[t] = bv - m*A;
  }
  __syncthreads();
  const int tx = t & 15, ty = t >> 4;
  const int lr = t >> 3, lk = (t & 7) * 4;
  float a00 = 0.f, a01 = 0.f, a10 = 0.f, a11 = 0.f;

  auto lda = [&](int k0) -> float4 {
    int gk = k0 + lk, gr = m0 + lr;
    const float* h = H1 + (size_t)gr*256;
    float4 h0 = *(const float4*)(h + gk);
    float4 h1 = *(const float4*)(h + gk + 128);
    float4 A0 = *(const float4*)(sA + gk);
    float4 B0 = *(const float4*)(sB + gk);
    float4 A1 = *(const float4*)(sA + gk + 128);
    float4 B1 = *(const float4*)(sB + gk + 128);
    float4 r;
    r.x = (h0.x*A0.x+B0.x) / (1.f + __expf(-(h1.x*A1.x+B1.x)));
    r.y = (h0.y*A0.y+B0.y) / (1.f + __expf(-(h1.y*A1.y+B1.y)));
    r.z = (h0.z*A0.z+B0.z) / (1.f + __expf(-(h1.z*A1.z+B1.z)));
    r.w = (h0.w*A0.w+B0.w) / (1.f + __expf(-(h1.w*A1.w+B1.w)));
    return r;
  };
  auto ldw = [&](int k0) -> float4 {
    return ld4(W, woff + (size_t)(n0 + lr) * 128 + k0 + lk, isbf);
  };

  float4 ra = lda(0), rw = ldw(0);
#pragma unroll 1
  for (int c = 0; c < 4; ++c){
    As[lk+0][lr] = ra.x; As[lk+1][lr] = ra.y; As[lk+2][lr] = ra.z; As[lk+3][lr] = ra.w;
    Ws[lk+0][lr] = rw.x; Ws[lk+1][lr] = rw.y; Ws[lk+2][lr] = rw.z; Ws[lk+3][lr] = rw.w;
    __syncthreads();
    float4 na = ra, nw = rw;
    if (c + 1 < 4){ na = lda((c+1) << 5); nw = ldw((c+1) << 5); }
#pragma unroll
    for (int kk = 0; kk < 32; ++kk){
      float2 av = *(const float2*)&As[kk][ty*2];
      float2 wv = *(const float2*)&Ws[kk][tx*2];
      a00 += av.x * wv.x; a01 += av.x * wv.y;
      a10 += av.y * wv.x; a11 += av.y * wv.y;
    }
    __syncthreads();
    ra = na; rw = nw;
  }
  int r0 = m0 + ty*2, c0 = n0 + tx*2;
  float* Cp = C + (size_t)r0 * 256 + c0;
  Cp[0] = a00; Cp[1] = a01; Cp[256] = a10; Cp[257] = a11;
}

// ---- merged group-stats + sparsemax + prior + loss + sparse xm, +drain ----
__global__ __launch_bounds__(256)
void spmax_k(const float* __restrict__ Ha, const void* __restrict__ gw,
             const void* __restrict__ gb, size_t goff, float* __restrict__ prior,
             const float* __restrict__ xn, const void* __restrict__ gmat,
             float* __restrict__ xm, float* __restrict__ lrow, int first,
             const float* __restrict__ st, float* __restrict__ amap, int dS, int dR0,
             const float* __restrict__ flg){
  int bid = blockIdx.x, t = threadIdx.x;
  if (bid >= 256){ drain_rows(st, amap, dS, dR0 + bid - 256, t); return; }
  __shared__ __align__(16) float sAA[256], sBA[256];
  __shared__ __align__(16) float tabs[4][256];
  __shared__ unsigned int msk[4][2];
  const int isbf = flg[0] != 0.0f;
  const int g = bid >> 5;
  {
    const float* Hp = Ha + (size_t)g*32768 + t;
    float s = 0.f, ss = 0.f;
#pragma unroll 8
    for (int i = 0; i < 128; ++i){ float v = Hp[(size_t)i*256]; s += v; ss += v*v; }
    float m = s * (1.f/128), is = rsqrtf(ss * (1.f/128) - m*m + BN_EPS_C);
    float wv = ldin(gw, goff + t, isbf), bv = ldin(gb, goff + t, isbf);
    float A = is * wv;
    sAA[t] = A; sBA[t] = bv - m*A;
  }
  __syncthreads();
  int lane = t & 63, wv = t >> 6;
  int b0 = bid * 4;
  int b = b0 + wv;
  size_t rb = (size_t)b * 256;
  int j0 = lane * 4;
  float4 h4 = *(const float4*)(Ha + rb + j0);
  float4 A4 = *(const float4*)(sAA + j0);
  float4 B4 = *(const float4*)(sBA + j0);
  float pr[4];
  if (first){ pr[0] = pr[1] = pr[2] = pr[3] = 1.f; }
  else { float4 p4 = *(const float4*)(prior + rb + j0); pr[0]=p4.x; pr[1]=p4.y; pr[2]=p4.z; pr[3]=p4.w; }
  float z[4];
  z[0] = (h4.x*A4.x + B4.x) * pr[0];
  z[1] = (h4.y*A4.y + B4.y) * pr[1];
  z[2] = (h4.z*A4.z + B4.z) * pr[2];
  z[3] = (h4.w*A4.w + B4.w) * pr[3];
  float zm = wmaxr(fmaxf(fmaxf(z[0], z[1]), fmaxf(z[2], z[3])));
  float lo = zm - 1.f, hi = zm;
#pragma unroll 1
  for (int it = 0; it < 30; ++it){
    float mid = 0.5f * (lo + hi);
    float sv = 0.f;
#pragma unroll
    for (int e = 0; e < 4; ++e){ float d = z[e] - mid; sv += d > 0.f ? d : 0.f; }
    sv = wsum(sv);
    if (sv >= 1.f) lo = mid; else hi = mid;
  }
  float tau = 0.5f * (lo + hi);
  float p[4], ls = 0.f;
#pragma unroll
  for (int e = 0; e < 4; ++e){
    p[e] = z[e] - tau; p[e] = p[e] > 0.f ? p[e] : 0.f;
    ls += p[e] * __logf(p[e] + 1e-15f);
  }
  *(float4*)&tabs[wv][j0] = make_float4(p[0], p[1], p[2], p[3]);
  *(float4*)(prior + rb + j0) = make_float4(pr[0]*(GAMMA_C-p[0]), pr[1]*(GAMMA_C-p[1]),
                                            pr[2]*(GAMMA_C-p[2]), pr[3]*(GAMMA_C-p[3]));
  ls = wsum(ls);
  if (lane == 0) lrow[b] = ls;
  bool nz = (p[0] > 0.f) | (p[1] > 0.f) | (p[2] > 0.f) | (p[3] > 0.f);
  unsigned long long bm = __ballot(nz);
  if (lane == 0){ msk[wv][0] = (unsigned int)bm; msk[wv][1] = (unsigned int)(bm >> 32); }
  __syncthreads();
  unsigned long long M0 = msk[0][0] | ((unsigned long long)msk[0][1] << 32);
  unsigned long long M1 = msk[1][0] | ((unsigned long long)msk[1][1] << 32);
  unsigned long long M2 = msk[2][0] | ((unsigned long long)msk[2][1] << 32);
  unsigned long long M3 = msk[3][0] | ((unsigned long long)msk[3][1] << 32);
  float a0 = 0.f, a1 = 0.f, a2 = 0.f, a3 = 0.f;
#pragma unroll 1
  for (int c = 0; c < 64; ++c){
    int r0a = (int)((M0 >> c) & 1), r1a = (int)((M1 >> c) & 1);
    int r2a = (int)((M2 >> c) & 1), r3a = (int)((M3 >> c) & 1);
    if (r0a | r1a | r2a | r3a){
      int k = c * 4;
      float g0 = ldin(gmat, (size_t)(k+0)*256 + t, isbf);
      float g1 = ldin(gmat, (size_t)(k+1)*256 + t, isbf);
      float g2 = ldin(gmat, (size_t)(k+2)*256 + t, isbf);
      float g3 = ldin(gmat, (size_t)(k+3)*256 + t, isbf);
      if (r0a){ float4 tv = *(float4*)&tabs[0][k]; a0 += tv.x*g0 + tv.y*g1 + tv.z*g2 + tv.w*g3; }
      if (r1a){ float4 tv = *(float4*)&tabs[1][k]; a1 += tv.x*g0 + tv.y*g1 + tv.z*g2 + tv.w*g3; }
      if (r2a){ float4 tv = *(float4*)&tabs[2][k]; a2 += tv.x*g0 + tv.y*g1 + tv.z*g2 + tv.w*g3; }
      if (r3a){ float4 tv = *(float4*)&tabs[3][k]; a3 += tv.x*g0 + tv.y*g1 + tv.z*g2 + tv.w*g3; }
    }
  }
  xm[(size_t)(b0+0)*256 + t] = a0 * xn[(size_t)(b0+0)*256 + t];
  xm[(size_t)(b0+1)*256 + t] = a1 * xn[(size_t)(b0+1)*256 + t];
  xm[(size_t)(b0+2)*256 + t] = a2 * xn[(size_t)(b0+2)*256 + t];
  xm[(size_t)(b0+3)*256 + t] = a3 * xn[(size_t)(b0+3)*256 + t];
}

// ---- attention pass A: y + softmax state (q,k,m,rz), +drain ---------------
__global__ __launch_bounds__(256)
void attnA_k(const float* __restrict__ xm, float* __restrict__ y,
             const void* __restrict__ siw, const void* __restrict__ sib,
             const void* __restrict__ sow, const void* __restrict__ sob,
             int s, float* __restrict__ st, float* __restrict__ amap, int dS, int dR0,
             const float* __restrict__ flg){
  int bid = blockIdx.x, t = threadIdx.x;
  if (bid >= 1024){ drain_rows(st, amap, dS, dR0 + bid - 1024, t); return; }
  __shared__ __align__(16) float ks[256], vs[256];
  __shared__ float r1[4], r2[4];
  const int isbf = flg[0] != 0.0f;
  int b = bid;
  float w0 = ldin(siw, s*3+0, isbf), w1 = ldin(siw, s*3+1, isbf), w2 = ldin(siw, s*3+2, isbf);
  float b0 = ldin(sib, s*3+0, isbf), b1 = ldin(sib, s*3+1, isbf), b2 = ldin(sib, s*3+2, isbf);
  float ow = ldin(sow, s, isbf), ob = ldin(sob, s, isbf);
  float xv = xm[(size_t)b*256 + t];
  float q = xv*w0 + b0, k = xv*w1 + b1, v = xv*w2 + b2;
  ks[t] = k; vs[t] = v;
  int lane = t & 63, wv = t >> 6;
  float km = wmaxr(k), kn = wminr(k);
  if (lane == 0){ r1[wv] = km; r2[wv] = kn; }
  __syncthreads();
  float kmax = fmaxf(fmaxf(r1[0], r1[1]), fmaxf(r1[2], r1[3]));
  float kmin = fminf(fminf(r2[0], r2[1]), fminf(r2[2], r2[3]));
  float mi = (q >= 0.f) ? q*kmax : q*kmin;
  float Z = 0.f, Y = 0.f;
#pragma unroll 8
  for (int j = 0; j < 256; j += 4){
    float4 k4 = *(const float4*)&ks[j];
    float4 v4 = *(const float4*)&vs[j];
    float e0 = __expf(q*k4.x - mi), e1 = __expf(q*k4.y - mi);
    float e2 = __expf(q*k4.z - mi), e3 = __expf(q*k4.w - mi);
    Z += (e0 + e1) + (e2 + e3);
    Y += (e0*v4.x + e1*v4.y) + (e2*v4.z + e3*v4.w);
  }
  float rz = 1.f / Z;
  y[(size_t)b*256 + t] = Y*rz*ow + ob;
  size_t sb = ((size_t)s*BATCH + b)*256 + t;
  st[sb]               = q;
  st[ST_STRIDE + sb]   = k;
  st[2*ST_STRIDE + sb] = mi;
  st[3*ST_STRIDE + sb] = rz;
}

// ---- merged 2x group-stats + combine (att + optional steps_out), +drain ---
__global__ __launch_bounds__(256)
void comb_k(const float* __restrict__ H1, const void* __restrict__ pw0,
            const void* __restrict__ pb0, size_t off0,
            const float* __restrict__ H2, const void* __restrict__ pw1,
            const void* __restrict__ pb1, size_t off1,
            float* __restrict__ att, float* __restrict__ steps,
            const float* __restrict__ st, float* __restrict__ amap, int dS, int dR0,
            const float* __restrict__ flg){
  int bid = blockIdx.x, t = threadIdx.x;
  if (bid >= 512){ drain_rows(st, amap, dS, dR0 + bid - 512, t); return; }
  __shared__ float sA0[256], sB0[256], sA1[256], sB1[256];
  const int isbf = flg[0] != 0.0f;
  const int g = bid >> 6;
  {
    const float* Hp = H1 + (size_t)g*32768 + t;
    float s = 0.f, ss = 0.f;
#pragma unroll 8
    for (int i = 0; i < 128; ++i){ float v = Hp[(size_t)i*256]; s += v; ss += v*v; }
    float m = s * (1.f/128), is = rsqrtf(ss * (1.f/128) - m*m + BN_EPS_C);
    float wv = ldin(pw0, off0 + t, isbf), bv = ldin(pb0, off0 + t, isbf);
    float A = is * wv;
    sA0[t] = A; sB0[t] = bv - m*A;
  }
  {
    const float* Hp = H2 + (size_t)g*32768 + t;
    float s = 0.f, ss = 0.f;
#pragma unroll 8
    for (int i = 0; i < 128; ++i){ float v = Hp[(size_t)i*256]; s += v; ss += v*v; }
    float m = s * (1.f/128), is = rsqrtf(ss * (1.f/128) - m*m + BN_EPS_C);
    float wv = ldin(pw1, off1 + t, isbf), bv = ldin(pb1, off1 + t, isbf);
    float A = is * wv;
    sA1[t] = A; sB1[t] = bv - m*A;
  }
  __syncthreads();
  int r = bid*2 + (t >> 7), j = t & 127;
  float h0 = H1[(size_t)r*256 + j], h1 = H1[(size_t)r*256 + j + 128];
  float u0 = h0 * sA0[j]     + sB0[j];
  float u1 = h1 * sA0[j+128] + sB0[j+128];
  float g0 = u0 / (1.f + __expf(-u1));
  float v0 = H2[(size_t)r*256 + j]     * sA1[j]     + sB1[j];
  float v1 = H2[(size_t)r*256 + j+128] * sA1[j+128] + sB1[j+128];
  float g1 = v0 / (1.f + __expf(-v1));
  float f = (g0 + g1) * SQRT_HALF_C;
  if (j < 64){
    if (steps) steps[(size_t)r*64 + j] = f > 0.f ? f : 0.01f*f;
  } else {
    att[(size_t)r*64 + (j - 64)] = f;
  }
}

// ---- final m_loss (+tail drains) -------------------------------------------
__global__ __launch_bounds__(256)
void mloss_k(const float* __restrict__ lrow, float* __restrict__ outp,
             const float* __restrict__ st, float* __restrict__ amap, int s, int row0){
  int bid = blockIdx.x, t = threadIdx.x;
  if (bid > 0){ drain_rows(st, amap, s, row0 + bid - 1, t); return; }
  __shared__ float sb[256];
  float v = 0.f;
  for (int i = t; i < N_STEPS*BATCH; i += 256) v += lrow[i];
  v = block_sum(v, sb);
  if (t == 0) outp[0] = v * (1.f/(N_STEPS*(float)BATCH));
}

extern "C" void kernel_launch(void* const* d_in, const int* in_sizes, int n_in,
                              void* d_out, int out_size, void* d_ws, size_t ws_size,
                              hipStream_t stream){
  const void* x         = d_in[0];
  const void* bemv      = d_in[1];
  const void* gmat      = d_in[2];
  const void* bn_w      = d_in[3];
  const void* bn_b      = d_in[4];
  const void* init_fc0  = d_in[5];
  const void* init_bnw0 = d_in[6];
  const void* init_bnb0 = d_in[7];
  const void* init_fc1  = d_in[8];
  const void* init_bnw1 = d_in[9];
  const void* init_bnb1 = d_in[10];
  const void* step_fc0  = d_in[11];
  const void* step_bnw0 = d_in[12];
  const void* step_bnb0 = d_in[13];
  const void* step_fc1  = d_in[14];
  const void* step_bnw1 = d_in[15];
  const void* step_bnb1 = d_in[16];
  const void* att_fc    = d_in[17];
  const void* att_bnw   = d_in[18];
  const void* att_bnb   = d_in[19];
  const void* sa_in_w   = d_in[20];
  const void* sa_in_b   = d_in[21];
  const void* sa_out_w  = d_in[22];
  const void* sa_out_b  = d_in[23];

  float* out       = (float*)d_out;
  float* steps_out = out;                               // 3*1024*64
  float* mloss_out = out + 196608;                      // 1
  float* amaps     = out + 196609;                      // 3*1024*256*256

  float* w     = (float*)d_ws;
  float* flag  = w;                   // [0,16)
  float* mean  = w + 16;              // 256
  float* istd  = w + 272;             // 256
  float* lrow  = w + 528;             // 3072
  float* xn    = w + 4096;            // 262144
  float* H1    = xn + 262144;
  float* H2    = H1 + 262144;
  float* att   = H2 + 262144;         // 65536
  float* xm    = att + 65536;         // 262144
  float* prior = xm + 262144;
  float* y     = prior + 262144;
  float* st    = y + 262144;          // 4 * ST_STRIDE = 3145728

  detect_k<<<1, 256, 0, stream>>>((const unsigned short*)x, flag);
  bnstats_k<<<256, 256, 0, stream>>>(x, mean, istd, flag);
  xn_k<<<1024, 256, 0, stream>>>(x, mean, istd, bn_w, bn_b, xn, flag);

  // initial feature transformer on [xn | bemv]
  gemm_bt_k<<<256, 256, 0, stream>>>(xn, bemv, 256, init_fc0, 0, H1, 512, st, amaps, 0, 0, flag);
  glugemm_k<<<256, 256, 0, stream>>>(H1, init_bnw0, init_bnb0, 0, init_fc1, 0, H2, st, amaps, 0, 0, flag);
  comb_k<<<512, 256, 0, stream>>>(H1, init_bnw0, init_bnb0, 0, H2, init_bnw1, init_bnb1, 0,
                                  att, nullptr, st, amaps, 0, 0, flag);

  for (int s = 0; s < N_STEPS; ++s){
    int pd = s - 1;
    int dn = (pd >= 0) ? 160 : 0;
    // A: a-GEMM K=64 on att -> H1 (pre-GBN "Ha")  [drains pd rows 544..704)
    gemm_bt_k<<<256 + dn, 256, 0, stream>>>(att, nullptr, 64, att_fc, (size_t)s*16384, H1, 64,
                                            st, amaps, pd, 544, flag);
    // C: stats + sparsemax + prior + loss + sparse xm  [drains pd rows 704..864)
    spmax_k<<<256 + dn, 256, 0, stream>>>(H1, att_bnw, att_bnb, (size_t)s*256, prior, xn, gmat,
                                          xm, lrow + s*1024, s == 0, st, amaps, pd, 704, flag);
    // D: attention pass A -> y + state  [drains pd rows 864..1024)
    attnA_k<<<1024 + dn, 256, 0, stream>>>(xm, y, sa_in_w, sa_in_b, sa_out_w, sa_out_b, s,
                                           st, amaps, pd, 864, flag);
    // E: step GEMM K=512 on [y|bemv] -> H1  [drains s rows 0..224)
    gemm_bt_k<<<256 + 224, 256, 0, stream>>>(y, bemv, 256, step_fc0, (size_t)s*131072, H1, 512,
                                             st, amaps, s, 0, flag);
    // G: stats + GLU GEMM K=128 -> H2  [drains s rows 224..384)
    glugemm_k<<<256 + 160, 256, 0, stream>>>(H1, step_bnw0, step_bnb0, (size_t)s*256,
                                             step_fc1, (size_t)s*32768, H2, st, amaps, s, 224, flag);
    // comb: stats x2 + combine -> att, steps_out[s]  [drains s rows 384..544)
    comb_k<<<512 + 160, 256, 0, stream>>>(H1, step_bnw0, step_bnb0, (size_t)s*256,
                                          H2, step_bnw1, step_bnb1, (size_t)s*256,
                                          att, steps_out + (size_t)s*65536, st, amaps, s, 384, flag);
  }
  // leftover amap rows for step 2 (480 rows) + m_loss
  mloss_k<<<481, 256, 0, stream>>>(lrow, mloss_out, st, amaps, 2, 544);
}

// Round 11
// 434.961 us; speedup vs baseline: 1.1702x; 1.1702x over previous
//
#include <hip/hip_runtime.h>
#include <hip/hip_bf16.h>

#define BATCH 1024
#define N_STEPS 3
#define GAMMA_C 1.3f
#define BN_EPS_C 1e-5f
#define SQRT_HALF_C 0.70710678118654752440f
#define ST_STRIDE 786432   // 3*1024*256 per state array

// ---- input loader: f32 or bf16 decided at runtime by detector flag --------
__device__ __forceinline__ float ldin(const void* p, size_t i, int isbf){
  if (isbf) return __bfloat162float(((const __hip_bfloat16*)p)[i]);
  return ((const float*)p)[i];
}
__device__ __forceinline__ float4 ld4(const void* p, size_t i, int isbf){
  if (!isbf) return *(const float4*)((const float*)p + i);
  const __hip_bfloat16* q = (const __hip_bfloat16*)p + i;
  return make_float4(__bfloat162float(q[0]), __bfloat162float(q[1]),
                     __bfloat162float(q[2]), __bfloat162float(q[3]));
}

// ---- wave (64-lane) butterfly reductions ----------------------------------
__device__ __forceinline__ float wsum(float v){
#pragma unroll
  for (int o = 32; o > 0; o >>= 1) v += __shfl_xor(v, o);
  return v;
}
__device__ __forceinline__ float wmaxr(float v){
#pragma unroll
  for (int o = 32; o > 0; o >>= 1) v = fmaxf(v, __shfl_xor(v, o));
  return v;
}
__device__ __forceinline__ float wminr(float v){
#pragma unroll
  for (int o = 32; o > 0; o >>= 1) v = fminf(v, __shfl_xor(v, o));
  return v;
}
__device__ __forceinline__ float block_sum(float v, float* sb){
  int t = threadIdx.x;
  sb[t] = v; __syncthreads();
#pragma unroll
  for (int s = 128; s > 0; s >>= 1){
    if (t < s) sb[t] += sb[t + s];
    __syncthreads();
  }
  float r = sb[0]; __syncthreads();
  return r;
}

// ---- amap drain: one block writes one (step, batch-row) amap tile ---------
// state layout: q | k | m | rz, each ST_STRIDE floats, indexed (s*1024+b)*256+i
// Aligned-float4 formulation: tile-local float offset l=3+4*(t+256j) is
// 16B-aligned (amaps base = out+196609). Each thread owns a fixed column
// quad cb=(3+4t)&255; per j the row is wave-uniform -> LDS broadcasts.
// Threads t%64==63 have a row-crossing quad (col 255 + next row cols 0-2),
// handled via operand selection in the SAME float4 store (no divergent
// stores). Thread 0 writes the 4 stray edge elements.
__device__ __forceinline__ void drain_rows(const float* __restrict__ st,
                                           float* __restrict__ amap,
                                           int s, int b, int t){
  __shared__ __align__(16) float sh[768];
  size_t sb = ((size_t)s*BATCH + b)*256;
  sh[t]       = st[sb + t];                  // q
  sh[256 + t] = st[2*ST_STRIDE + sb + t];    // m
  sh[512 + t] = st[3*ST_STRIDE + sb + t];    // rz
  __syncthreads();
  const float* kS = st + ST_STRIDE + sb;
  float* tp = amap + ((size_t)s*BATCH + b)*65536;
  int cb  = (3 + 4*t) & 255;
  int rb0 = (3 + 4*t) >> 8;
  float k0 = kS[cb];
  float k1 = kS[(cb+1) & 255];
  float k2 = kS[(cb+2) & 255];
  float k3 = kS[(cb+3) & 255];
  const bool cross = (cb == 255);
  const int nj = (t < 255) ? 64 : 63;
#pragma unroll 4
  for (int j = 0; j < nj; ++j){
    int r0 = 4*j + rb0;
    float q0 = sh[r0], m0 = sh[256+r0], z0 = sh[512+r0];
    float4 o;
    if (!cross){
      o.x = __expf(q0*k0 - m0) * z0;
      o.y = __expf(q0*k1 - m0) * z0;
      o.z = __expf(q0*k2 - m0) * z0;
      o.w = __expf(q0*k3 - m0) * z0;
    } else {
      float q1 = sh[r0+1], m1 = sh[256+r0+1], z1 = sh[512+r0+1];
      o.x = __expf(q0*k0 - m0) * z0;
      o.y = __expf(q1*k1 - m1) * z1;
      o.z = __expf(q1*k2 - m1) * z1;
      o.w = __expf(q1*k3 - m1) * z1;
    }
    *(float4*)(tp + 3 + 4*t + 1024*j) = o;
  }
  if (t == 0){
    float q0 = sh[0], m0 = sh[256], z0 = sh[512];
    tp[0] = __expf(q0*kS[0] - m0) * z0;
    tp[1] = __expf(q0*kS[1] - m0) * z0;
    tp[2] = __expf(q0*kS[2] - m0) * z0;
    float qL = sh[255], mL = sh[511], zL = sh[767];
    tp[65535] = __expf(qL*kS[255] - mL) * zL;
  }
}

// ---- dtype detector --------------------------------------------------------
__global__ void detect_k(const unsigned short* __restrict__ u, float* __restrict__ flag){
  __shared__ int cnt;
  if (threadIdx.x == 0) cnt = 0;
  __syncthreads();
  int c = 0;
  for (int j = 0; j < 16; ++j){
    unsigned short v = u[(size_t)(threadIdx.x * 16 + j) * 2];
    int e = (v >> 7) & 0xFF;
    if (e >= 118 && e <= 134) c++;
  }
  atomicAdd(&cnt, c);
  __syncthreads();
  if (threadIdx.x == 0) flag[0] = (cnt > 2048) ? 1.0f : 0.0f;
}

// ---- full-batch BN stats ---------------------------------------------------
__global__ void bnstats_k(const void* __restrict__ x, float* __restrict__ mean,
                          float* __restrict__ istd, const float* __restrict__ flg){
  __shared__ float sb[256];
  const int isbf = flg[0] != 0.0f;
  int f = blockIdx.x, t = threadIdx.x;
  float s = 0.f, ss = 0.f;
  for (int r = t; r < BATCH; r += 256){
    float v = ldin(x, (size_t)r * 256 + f, isbf);
    s += v; ss += v * v;
  }
  s  = block_sum(s, sb);
  ss = block_sum(ss, sb);
  if (t == 0){
    float m = s * (1.f / BATCH);
    mean[f] = m;
    istd[f] = rsqrtf(ss * (1.f / BATCH) - m * m + BN_EPS_C);
  }
}

__global__ void xn_k(const void* __restrict__ x, const float* __restrict__ mean,
                     const float* __restrict__ istd, const void* __restrict__ bw,
                     const void* __restrict__ bb, float* __restrict__ xn,
                     const float* __restrict__ flg){
  const int isbf = flg[0] != 0.0f;
  int idx = blockIdx.x * 256 + threadIdx.x;
  int f = idx & 255;
  xn[idx] = (ldin(x, idx, isbf) - mean[f]) * istd[f] * ldin(bw, f, isbf) + ldin(bb, f, isbf);
}

// ---- GEMM (BT): C(1024x256) = [A1|A2](1024xK) @ W^T, 1D grid, +drain ------
__global__ __launch_bounds__(256)
void gemm_bt_k(const float* __restrict__ A1, const void* __restrict__ A2, int split,
               const void* __restrict__ W, size_t woff, float* __restrict__ C, int K,
               const float* __restrict__ st, float* __restrict__ amap, int dS, int dR0,
               const float* __restrict__ flg){
  int bid = blockIdx.x, t = threadIdx.x;
  if (bid >= 256){ drain_rows(st, amap, dS, dR0 + bid - 256, t); return; }
  __shared__ float As[32][34];
  __shared__ float Ws[32][34];
  const int isbf = flg[0] != 0.0f;
  const int n0 = (bid & 7) * 32, m0 = (bid >> 3) * 32;
  const int tx = t & 15, ty = t >> 4;
  const int lr = t >> 3, lk = (t & 7) * 4;
  const int nc = K >> 5;
  float a00 = 0.f, a01 = 0.f, a10 = 0.f, a11 = 0.f;

  auto lda = [&](int k0) -> float4 {
    int gk = k0 + lk, gr = m0 + lr;
    if (gk < split) return *(const float4*)(A1 + (size_t)gr * split + gk);
    return ld4(A2, (size_t)gr * (K - split) + (gk - split), isbf);
  };
  auto ldw = [&](int k0) -> float4 {
    return ld4(W, woff + (size_t)(n0 + lr) * K + k0 + lk, isbf);
  };

  float4 ra = lda(0), rw = ldw(0);
  for (int c = 0; c < nc; ++c){
    As[lk+0][lr] = ra.x; As[lk+1][lr] = ra.y; As[lk+2][lr] = ra.z; As[lk+3][lr] = ra.w;
    Ws[lk+0][lr] = rw.x; Ws[lk+1][lr] = rw.y; Ws[lk+2][lr] = rw.z; Ws[lk+3][lr] = rw.w;
    __syncthreads();
    float4 na = ra, nw = rw;
    if (c + 1 < nc){ na = lda((c+1) << 5); nw = ldw((c+1) << 5); }
#pragma unroll
    for (int kk = 0; kk < 32; ++kk){
      float2 av = *(const float2*)&As[kk][ty*2];
      float2 wv = *(const float2*)&Ws[kk][tx*2];
      a00 += av.x * wv.x; a01 += av.x * wv.y;
      a10 += av.y * wv.x; a11 += av.y * wv.y;
    }
    __syncthreads();
    ra = na; rw = nw;
  }
  int r0 = m0 + ty*2, c0 = n0 + tx*2;
  float* Cp = C + (size_t)r0 * 256 + c0;
  Cp[0] = a00; Cp[1] = a01; Cp[256] = a10; Cp[257] = a11;
}

// ---- merged group-stats + GLU-fused GEMM K=128 -> H2, +drain --------------
__global__ __launch_bounds__(256)
void glugemm_k(const float* __restrict__ H1, const void* __restrict__ gw,
               const void* __restrict__ gb, size_t goff,
               const void* __restrict__ W, size_t woff, float* __restrict__ C,
               const float* __restrict__ st, float* __restrict__ amap, int dS, int dR0,
               const float* __restrict__ flg){
  int bid = blockIdx.x, t = threadIdx.x;
  if (bid >= 256){ drain_rows(st, amap, dS, dR0 + bid - 256, t); return; }
  __shared__ __align__(16) float sA[256], sB[256];
  __shared__ float As[32][34];
  __shared__ float Ws[32][34];
  const int isbf = flg[0] != 0.0f;
  const int n0 = (bid & 7) * 32, m0 = (bid >> 3) * 32;
  const int g = bid >> 5;
  {
    const float* Hp = H1 + (size_t)g*32768 + t;
    float s = 0.f, ss = 0.f;
#pragma unroll 8
    for (int i = 0; i < 128; ++i){ float v = Hp[(size_t)i*256]; s += v; ss += v*v; }
    float m = s * (1.f/128), is = rsqrtf(ss * (1.f/128) - m*m + BN_EPS_C);
    float wv = ldin(gw, goff + t, isbf), bv = ldin(gb, goff + t, isbf);
    float A = is * wv;
    sA[t] = A; sB[t] = bv - m*A;
  }
  __syncthreads();
  const int tx = t & 15, ty = t >> 4;
  const int lr = t >> 3, lk = (t & 7) * 4;
  float a00 = 0.f, a01 = 0.f, a10 = 0.f, a11 = 0.f;

  auto lda = [&](int k0) -> float4 {
    int gk = k0 + lk, gr = m0 + lr;
    const float* h = H1 + (size_t)gr*256;
    float4 h0 = *(const float4*)(h + gk);
    float4 h1 = *(const float4*)(h + gk + 128);
    float4 A0 = *(const float4*)(sA + gk);
    float4 B0 = *(const float4*)(sB + gk);
    float4 A1 = *(const float4*)(sA + gk + 128);
    float4 B1 = *(const float4*)(sB + gk + 128);
    float4 r;
    r.x = (h0.x*A0.x+B0.x) / (1.f + __expf(-(h1.x*A1.x+B1.x)));
    r.y = (h0.y*A0.y+B0.y) / (1.f + __expf(-(h1.y*A1.y+B1.y)));
    r.z = (h0.z*A0.z+B0.z) / (1.f + __expf(-(h1.z*A1.z+B1.z)));
    r.w = (h0.w*A0.w+B0.w) / (1.f + __expf(-(h1.w*A1.w+B1.w)));
    return r;
  };
  auto ldw = [&](int k0) -> float4 {
    return ld4(W, woff + (size_t)(n0 + lr) * 128 + k0 + lk, isbf);
  };

  float4 ra = lda(0), rw = ldw(0);
#pragma unroll 1
  for (int c = 0; c < 4; ++c){
    As[lk+0][lr] = ra.x; As[lk+1][lr] = ra.y; As[lk+2][lr] = ra.z; As[lk+3][lr] = ra.w;
    Ws[lk+0][lr] = rw.x; Ws[lk+1][lr] = rw.y; Ws[lk+2][lr] = rw.z; Ws[lk+3][lr] = rw.w;
    __syncthreads();
    float4 na = ra, nw = rw;
    if (c + 1 < 4){ na = lda((c+1) << 5); nw = ldw((c+1) << 5); }
#pragma unroll
    for (int kk = 0; kk < 32; ++kk){
      float2 av = *(const float2*)&As[kk][ty*2];
      float2 wv = *(const float2*)&Ws[kk][tx*2];
      a00 += av.x * wv.x; a01 += av.x * wv.y;
      a10 += av.y * wv.x; a11 += av.y * wv.y;
    }
    __syncthreads();
    ra = na; rw = nw;
  }
  int r0 = m0 + ty*2, c0 = n0 + tx*2;
  float* Cp = C + (size_t)r0 * 256 + c0;
  Cp[0] = a00; Cp[1] = a01; Cp[256] = a10; Cp[257] = a11;
}

// ---- merged group-stats + sparsemax + prior + loss + sparse xm, +drain ----
__global__ __launch_bounds__(256)
void spmax_k(const float* __restrict__ Ha, const void* __restrict__ gw,
             const void* __restrict__ gb, size_t goff, float* __restrict__ prior,
             const float* __restrict__ xn, const void* __restrict__ gmat,
             float* __restrict__ xm, float* __restrict__ lrow, int first,
             const float* __restrict__ st, float* __restrict__ amap, int dS, int dR0,
             const float* __restrict__ flg){
  int bid = blockIdx.x, t = threadIdx.x;
  if (bid >= 256){ drain_rows(st, amap, dS, dR0 + bid - 256, t); return; }
  __shared__ __align__(16) float sAA[256], sBA[256];
  __shared__ __align__(16) float tabs[4][256];
  __shared__ unsigned int msk[4][2];
  const int isbf = flg[0] != 0.0f;
  const int g = bid >> 5;
  {
    const float* Hp = Ha + (size_t)g*32768 + t;
    float s = 0.f, ss = 0.f;
#pragma unroll 8
    for (int i = 0; i < 128; ++i){ float v = Hp[(size_t)i*256]; s += v; ss += v*v; }
    float m = s * (1.f/128), is = rsqrtf(ss * (1.f/128) - m*m + BN_EPS_C);
    float wv = ldin(gw, goff + t, isbf), bv = ldin(gb, goff + t, isbf);
    float A = is * wv;
    sAA[t] = A; sBA[t] = bv - m*A;
  }
  __syncthreads();
  int lane = t & 63, wv = t >> 6;
  int b0 = bid * 4;
  int b = b0 + wv;
  size_t rb = (size_t)b * 256;
  int j0 = lane * 4;
  float4 h4 = *(const float4*)(Ha + rb + j0);
  float4 A4 = *(const float4*)(sAA + j0);
  float4 B4 = *(const float4*)(sBA + j0);
  float pr[4];
  if (first){ pr[0] = pr[1] = pr[2] = pr[3] = 1.f; }
  else { float4 p4 = *(const float4*)(prior + rb + j0); pr[0]=p4.x; pr[1]=p4.y; pr[2]=p4.z; pr[3]=p4.w; }
  float z[4];
  z[0] = (h4.x*A4.x + B4.x) * pr[0];
  z[1] = (h4.y*A4.y + B4.y) * pr[1];
  z[2] = (h4.z*A4.z + B4.z) * pr[2];
  z[3] = (h4.w*A4.w + B4.w) * pr[3];
  float zm = wmaxr(fmaxf(fmaxf(z[0], z[1]), fmaxf(z[2], z[3])));
  float lo = zm - 1.f, hi = zm;
#pragma unroll 1
  for (int it = 0; it < 30; ++it){
    float mid = 0.5f * (lo + hi);
    float sv = 0.f;
#pragma unroll
    for (int e = 0; e < 4; ++e){ float d = z[e] - mid; sv += d > 0.f ? d : 0.f; }
    sv = wsum(sv);
    if (sv >= 1.f) lo = mid; else hi = mid;
  }
  float tau = 0.5f * (lo + hi);
  float p[4], ls = 0.f;
#pragma unroll
  for (int e = 0; e < 4; ++e){
    p[e] = z[e] - tau; p[e] = p[e] > 0.f ? p[e] : 0.f;
    ls += p[e] * __logf(p[e] + 1e-15f);
  }
  *(float4*)&tabs[wv][j0] = make_float4(p[0], p[1], p[2], p[3]);
  *(float4*)(prior + rb + j0) = make_float4(pr[0]*(GAMMA_C-p[0]), pr[1]*(GAMMA_C-p[1]),
                                            pr[2]*(GAMMA_C-p[2]), pr[3]*(GAMMA_C-p[3]));
  ls = wsum(ls);
  if (lane == 0) lrow[b] = ls;
  bool nz = (p[0] > 0.f) | (p[1] > 0.f) | (p[2] > 0.f) | (p[3] > 0.f);
  unsigned long long bm = __ballot(nz);
  if (lane == 0){ msk[wv][0] = (unsigned int)bm; msk[wv][1] = (unsigned int)(bm >> 32); }
  __syncthreads();
  unsigned long long M0 = msk[0][0] | ((unsigned long long)msk[0][1] << 32);
  unsigned long long M1 = msk[1][0] | ((unsigned long long)msk[1][1] << 32);
  unsigned long long M2 = msk[2][0] | ((unsigned long long)msk[2][1] << 32);
  unsigned long long M3 = msk[3][0] | ((unsigned long long)msk[3][1] << 32);
  float a0 = 0.f, a1 = 0.f, a2 = 0.f, a3 = 0.f;
#pragma unroll 1
  for (int c = 0; c < 64; ++c){
    int r0a = (int)((M0 >> c) & 1), r1a = (int)((M1 >> c) & 1);
    int r2a = (int)((M2 >> c) & 1), r3a = (int)((M3 >> c) & 1);
    if (r0a | r1a | r2a | r3a){
      int k = c * 4;
      float g0 = ldin(gmat, (size_t)(k+0)*256 + t, isbf);
      float g1 = ldin(gmat, (size_t)(k+1)*256 + t, isbf);
      float g2 = ldin(gmat, (size_t)(k+2)*256 + t, isbf);
      float g3 = ldin(gmat, (size_t)(k+3)*256 + t, isbf);
      if (r0a){ float4 tv = *(float4*)&tabs[0][k]; a0 += tv.x*g0 + tv.y*g1 + tv.z*g2 + tv.w*g3; }
      if (r1a){ float4 tv = *(float4*)&tabs[1][k]; a1 += tv.x*g0 + tv.y*g1 + tv.z*g2 + tv.w*g3; }
      if (r2a){ float4 tv = *(float4*)&tabs[2][k]; a2 += tv.x*g0 + tv.y*g1 + tv.z*g2 + tv.w*g3; }
      if (r3a){ float4 tv = *(float4*)&tabs[3][k]; a3 += tv.x*g0 + tv.y*g1 + tv.z*g2 + tv.w*g3; }
    }
  }
  xm[(size_t)(b0+0)*256 + t] = a0 * xn[(size_t)(b0+0)*256 + t];
  xm[(size_t)(b0+1)*256 + t] = a1 * xn[(size_t)(b0+1)*256 + t];
  xm[(size_t)(b0+2)*256 + t] = a2 * xn[(size_t)(b0+2)*256 + t];
  xm[(size_t)(b0+3)*256 + t] = a3 * xn[(size_t)(b0+3)*256 + t];
}

// ---- attention pass A: y + softmax state (q,k,m,rz), +drain ---------------
__global__ __launch_bounds__(256)
void attnA_k(const float* __restrict__ xm, float* __restrict__ y,
             const void* __restrict__ siw, const void* __restrict__ sib,
             const void* __restrict__ sow, const void* __restrict__ sob,
             int s, float* __restrict__ st, float* __restrict__ amap, int dS, int dR0,
             const float* __restrict__ flg){
  int bid = blockIdx.x, t = threadIdx.x;
  if (bid >= 1024){ drain_rows(st, amap, dS, dR0 + bid - 1024, t); return; }
  __shared__ __align__(16) float ks[256], vs[256];
  __shared__ float r1[4], r2[4];
  const int isbf = flg[0] != 0.0f;
  int b = bid;
  float w0 = ldin(siw, s*3+0, isbf), w1 = ldin(siw, s*3+1, isbf), w2 = ldin(siw, s*3+2, isbf);
  float b0 = ldin(sib, s*3+0, isbf), b1 = ldin(sib, s*3+1, isbf), b2 = ldin(sib, s*3+2, isbf);
  float ow = ldin(sow, s, isbf), ob = ldin(sob, s, isbf);
  float xv = xm[(size_t)b*256 + t];
  float q = xv*w0 + b0, k = xv*w1 + b1, v = xv*w2 + b2;
  ks[t] = k; vs[t] = v;
  int lane = t & 63, wv = t >> 6;
  float km = wmaxr(k), kn = wminr(k);
  if (lane == 0){ r1[wv] = km; r2[wv] = kn; }
  __syncthreads();
  float kmax = fmaxf(fmaxf(r1[0], r1[1]), fmaxf(r1[2], r1[3]));
  float kmin = fminf(fminf(r2[0], r2[1]), fminf(r2[2], r2[3]));
  float mi = (q >= 0.f) ? q*kmax : q*kmin;
  float Z = 0.f, Y = 0.f;
#pragma unroll 8
  for (int j = 0; j < 256; j += 4){
    float4 k4 = *(const float4*)&ks[j];
    float4 v4 = *(const float4*)&vs[j];
    float e0 = __expf(q*k4.x - mi), e1 = __expf(q*k4.y - mi);
    float e2 = __expf(q*k4.z - mi), e3 = __expf(q*k4.w - mi);
    Z += (e0 + e1) + (e2 + e3);
    Y += (e0*v4.x + e1*v4.y) + (e2*v4.z + e3*v4.w);
  }
  float rz = 1.f / Z;
  y[(size_t)b*256 + t] = Y*rz*ow + ob;
  size_t sb = ((size_t)s*BATCH + b)*256 + t;
  st[sb]               = q;
  st[ST_STRIDE + sb]   = k;
  st[2*ST_STRIDE + sb] = mi;
  st[3*ST_STRIDE + sb] = rz;
}

// ---- merged 2x group-stats + combine (att + optional steps_out), +drain ---
__global__ __launch_bounds__(256)
void comb_k(const float* __restrict__ H1, const void* __restrict__ pw0,
            const void* __restrict__ pb0, size_t off0,
            const float* __restrict__ H2, const void* __restrict__ pw1,
            const void* __restrict__ pb1, size_t off1,
            float* __restrict__ att, float* __restrict__ steps,
            const float* __restrict__ st, float* __restrict__ amap, int dS, int dR0,
            const float* __restrict__ flg){
  int bid = blockIdx.x, t = threadIdx.x;
  if (bid >= 512){ drain_rows(st, amap, dS, dR0 + bid - 512, t); return; }
  __shared__ float sA0[256], sB0[256], sA1[256], sB1[256];
  const int isbf = flg[0] != 0.0f;
  const int g = bid >> 6;
  {
    const float* Hp = H1 + (size_t)g*32768 + t;
    float s = 0.f, ss = 0.f;
#pragma unroll 8
    for (int i = 0; i < 128; ++i){ float v = Hp[(size_t)i*256]; s += v; ss += v*v; }
    float m = s * (1.f/128), is = rsqrtf(ss * (1.f/128) - m*m + BN_EPS_C);
    float wv = ldin(pw0, off0 + t, isbf), bv = ldin(pb0, off0 + t, isbf);
    float A = is * wv;
    sA0[t] = A; sB0[t] = bv - m*A;
  }
  {
    const float* Hp = H2 + (size_t)g*32768 + t;
    float s = 0.f, ss = 0.f;
#pragma unroll 8
    for (int i = 0; i < 128; ++i){ float v = Hp[(size_t)i*256]; s += v; ss += v*v; }
    float m = s * (1.f/128), is = rsqrtf(ss * (1.f/128) - m*m + BN_EPS_C);
    float wv = ldin(pw1, off1 + t, isbf), bv = ldin(pb1, off1 + t, isbf);
    float A = is * wv;
    sA1[t] = A; sB1[t] = bv - m*A;
  }
  __syncthreads();
  int r = bid*2 + (t >> 7), j = t & 127;
  float h0 = H1[(size_t)r*256 + j], h1 = H1[(size_t)r*256 + j + 128];
  float u0 = h0 * sA0[j]     + sB0[j];
  float u1 = h1 * sA0[j+128] + sB0[j+128];
  float g0 = u0 / (1.f + __expf(-u1));
  float v0 = H2[(size_t)r*256 + j]     * sA1[j]     + sB1[j];
  float v1 = H2[(size_t)r*256 + j+128] * sA1[j+128] + sB1[j+128];
  float g1 = v0 / (1.f + __expf(-v1));
  float f = (g0 + g1) * SQRT_HALF_C;
  if (j < 64){
    if (steps) steps[(size_t)r*64 + j] = f > 0.f ? f : 0.01f*f;
  } else {
    att[(size_t)r*64 + (j - 64)] = f;
  }
}

// ---- final m_loss (+tail drains) -------------------------------------------
__global__ __launch_bounds__(256)
void mloss_k(const float* __restrict__ lrow, float* __restrict__ outp,
             const float* __restrict__ st, float* __restrict__ amap, int s, int row0){
  int bid = blockIdx.x, t = threadIdx.x;
  if (bid > 0){ drain_rows(st, amap, s, row0 + bid - 1, t); return; }
  __shared__ float sb[256];
  float v = 0.f;
  for (int i = t; i < N_STEPS*BATCH; i += 256) v += lrow[i];
  v = block_sum(v, sb);
  if (t == 0) outp[0] = v * (1.f/(N_STEPS*(float)BATCH));
}

extern "C" void kernel_launch(void* const* d_in, const int* in_sizes, int n_in,
                              void* d_out, int out_size, void* d_ws, size_t ws_size,
                              hipStream_t stream){
  const void* x         = d_in[0];
  const void* bemv      = d_in[1];
  const void* gmat      = d_in[2];
  const void* bn_w      = d_in[3];
  const void* bn_b      = d_in[4];
  const void* init_fc0  = d_in[5];
  const void* init_bnw0 = d_in[6];
  const void* init_bnb0 = d_in[7];
  const void* init_fc1  = d_in[8];
  const void* init_bnw1 = d_in[9];
  const void* init_bnb1 = d_in[10];
  const void* step_fc0  = d_in[11];
  const void* step_bnw0 = d_in[12];
  const void* step_bnb0 = d_in[13];
  const void* step_fc1  = d_in[14];
  const void* step_bnw1 = d_in[15];
  const void* step_bnb1 = d_in[16];
  const void* att_fc    = d_in[17];
  const void* att_bnw   = d_in[18];
  const void* att_bnb   = d_in[19];
  const void* sa_in_w   = d_in[20];
  const void* sa_in_b   = d_in[21];
  const void* sa_out_w  = d_in[22];
  const void* sa_out_b  = d_in[23];

  float* out       = (float*)d_out;
  float* steps_out = out;                               // 3*1024*64
  float* mloss_out = out + 196608;                      // 1
  float* amaps     = out + 196609;                      // 3*1024*256*256

  float* w     = (float*)d_ws;
  float* flag  = w;                   // [0,16)
  float* mean  = w + 16;              // 256
  float* istd  = w + 272;             // 256
  float* lrow  = w + 528;             // 3072
  float* xn    = w + 4096;            // 262144
  float* H1    = xn + 262144;
  float* H2    = H1 + 262144;
  float* att   = H2 + 262144;         // 65536
  float* xm    = att + 65536;         // 262144
  float* prior = xm + 262144;
  float* y     = prior + 262144;
  float* st    = y + 262144;          // 4 * ST_STRIDE = 3145728

  detect_k<<<1, 256, 0, stream>>>((const unsigned short*)x, flag);
  bnstats_k<<<256, 256, 0, stream>>>(x, mean, istd, flag);
  xn_k<<<1024, 256, 0, stream>>>(x, mean, istd, bn_w, bn_b, xn, flag);

  // initial feature transformer on [xn | bemv]
  gemm_bt_k<<<256, 256, 0, stream>>>(xn, bemv, 256, init_fc0, 0, H1, 512, st, amaps, 0, 0, flag);
  glugemm_k<<<256, 256, 0, stream>>>(H1, init_bnw0, init_bnb0, 0, init_fc1, 0, H2, st, amaps, 0, 0, flag);
  comb_k<<<512, 256, 0, stream>>>(H1, init_bnw0, init_bnb0, 0, H2, init_bnw1, init_bnb1, 0,
                                  att, nullptr, st, amaps, 0, 0, flag);

  for (int s = 0; s < N_STEPS; ++s){
    int pd = s - 1;
    int dn = (pd >= 0) ? 160 : 0;
    // A: a-GEMM K=64 on att -> H1 (pre-GBN "Ha")  [drains pd rows 544..704)
    gemm_bt_k<<<256 + dn, 256, 0, stream>>>(att, nullptr, 64, att_fc, (size_t)s*16384, H1, 64,
                                            st, amaps, pd, 544, flag);
    // C: stats + sparsemax + prior + loss + sparse xm  [drains pd rows 704..864)
    spmax_k<<<256 + dn, 256, 0, stream>>>(H1, att_bnw, att_bnb, (size_t)s*256, prior, xn, gmat,
                                          xm, lrow + s*1024, s == 0, st, amaps, pd, 704, flag);
    // D: attention pass A -> y + state  [drains pd rows 864..1024)
    attnA_k<<<1024 + dn, 256, 0, stream>>>(xm, y, sa_in_w, sa_in_b, sa_out_w, sa_out_b, s,
                                           st, amaps, pd, 864, flag);
    // E: step GEMM K=512 on [y|bemv] -> H1  [drains s rows 0..224)
    gemm_bt_k<<<256 + 224, 256, 0, stream>>>(y, bemv, 256, step_fc0, (size_t)s*131072, H1, 512,
                                             st, amaps, s, 0, flag);
    // G: stats + GLU GEMM K=128 -> H2  [drains s rows 224..384)
    glugemm_k<<<256 + 160, 256, 0, stream>>>(H1, step_bnw0, step_bnb0, (size_t)s*256,
                                             step_fc1, (size_t)s*32768, H2, st, amaps, s, 224, flag);
    // comb: stats x2 + combine -> att, steps_out[s]  [drains s rows 384..544)
    comb_k<<<512 + 160, 256, 0, stream>>>(H1, step_bnw0, step_bnb0, (size_t)s*256,
                                          H2, step_bnw1, step_bnb1, (size_t)s*256,
                                          att, steps_out + (size_t)s*65536, st, amaps, s, 384, flag);
  }
  // leftover amap rows for step 2 (480 rows) + m_loss
  mloss_k<<<481, 256, 0, stream>>>(lrow, mloss_out, st, amaps, 2, 544);
}

// Round 12
// 380.960 us; speedup vs baseline: 1.3361x; 1.1418x over previous
//
#include <hip/hip_runtime.h>
#include <hip/hip_bf16.h>

#define BATCH 1024
#define N_STEPS 3
#define GAMMA_C 1.3f
#define BN_EPS_C 1e-5f
#define SQRT_HALF_C 0.70710678118654752440f
#define ST_STRIDE 786432   // 3*1024*256 per state array

// ---- input loader: f32 or bf16 decided at runtime by detector flag --------
__device__ __forceinline__ float ldin(const void* p, size_t i, int isbf){
  if (isbf) return __bfloat162float(((const __hip_bfloat16*)p)[i]);
  return ((const float*)p)[i];
}
__device__ __forceinline__ float4 ld4(const void* p, size_t i, int isbf){
  if (!isbf) return *(const float4*)((const float*)p + i);
  const __hip_bfloat16* q = (const __hip_bfloat16*)p + i;
  return make_float4(__bfloat162float(q[0]), __bfloat162float(q[1]),
                     __bfloat162float(q[2]), __bfloat162float(q[3]));
}

// ---- wave (64-lane) butterfly reductions ----------------------------------
__device__ __forceinline__ float wsum(float v){
#pragma unroll
  for (int o = 32; o > 0; o >>= 1) v += __shfl_xor(v, o);
  return v;
}
__device__ __forceinline__ float wmaxr(float v){
#pragma unroll
  for (int o = 32; o > 0; o >>= 1) v = fmaxf(v, __shfl_xor(v, o));
  return v;
}
__device__ __forceinline__ float wminr(float v){
#pragma unroll
  for (int o = 32; o > 0; o >>= 1) v = fminf(v, __shfl_xor(v, o));
  return v;
}
__device__ __forceinline__ float block_sum(float v, float* sb){
  int t = threadIdx.x;
  sb[t] = v; __syncthreads();
#pragma unroll
  for (int s = 128; s > 0; s >>= 1){
    if (t < s) sb[t] += sb[t + s];
    __syncthreads();
  }
  float r = sb[0]; __syncthreads();
  return r;
}

// ---- amap drain (r11 aligned-float4 formulation, proven) ------------------
__device__ __forceinline__ void drain_rows(const float* __restrict__ st,
                                           float* __restrict__ amap,
                                           int s, int b, int t){
  __shared__ __align__(16) float sh[768];
  size_t sb = ((size_t)s*BATCH + b)*256;
  sh[t]       = st[sb + t];                  // q
  sh[256 + t] = st[2*ST_STRIDE + sb + t];    // m
  sh[512 + t] = st[3*ST_STRIDE + sb + t];    // rz
  __syncthreads();
  const float* kS = st + ST_STRIDE + sb;
  float* tp = amap + ((size_t)s*BATCH + b)*65536;
  int cb  = (3 + 4*t) & 255;
  int rb0 = (3 + 4*t) >> 8;
  float k0 = kS[cb];
  float k1 = kS[(cb+1) & 255];
  float k2 = kS[(cb+2) & 255];
  float k3 = kS[(cb+3) & 255];
  const bool cross = (cb == 255);
  const int nj = (t < 255) ? 64 : 63;
#pragma unroll 4
  for (int j = 0; j < nj; ++j){
    int r0 = 4*j + rb0;
    float q0 = sh[r0], m0 = sh[256+r0], z0 = sh[512+r0];
    float4 o;
    if (!cross){
      o.x = __expf(q0*k0 - m0) * z0;
      o.y = __expf(q0*k1 - m0) * z0;
      o.z = __expf(q0*k2 - m0) * z0;
      o.w = __expf(q0*k3 - m0) * z0;
    } else {
      float q1 = sh[r0+1], m1 = sh[256+r0+1], z1 = sh[512+r0+1];
      o.x = __expf(q0*k0 - m0) * z0;
      o.y = __expf(q1*k1 - m1) * z1;
      o.z = __expf(q1*k2 - m1) * z1;
      o.w = __expf(q1*k3 - m1) * z1;
    }
    *(float4*)(tp + 3 + 4*t + 1024*j) = o;
  }
  if (t == 0){
    float q0 = sh[0], m0 = sh[256], z0 = sh[512];
    tp[0] = __expf(q0*kS[0] - m0) * z0;
    tp[1] = __expf(q0*kS[1] - m0) * z0;
    tp[2] = __expf(q0*kS[2] - m0) * z0;
    float qL = sh[255], mL = sh[511], zL = sh[767];
    tp[65535] = __expf(qL*kS[255] - mL) * zL;
  }
}

// ---- bnstats + detector + per-feature affine ------------------------------
__global__ __launch_bounds__(256)
void bnstatsD_k(const void* __restrict__ x, const void* __restrict__ bnw,
                const void* __restrict__ bnb, float* __restrict__ xnA,
                float* __restrict__ xnB, float* __restrict__ flag){
  __shared__ float sb[256];
  __shared__ int cnt;
  int f = blockIdx.x, t = threadIdx.x;
  if (t == 0) cnt = 0;
  __syncthreads();
  const unsigned short* u = (const unsigned short*)x;
  int c = 0;
  for (int j = 0; j < 16; ++j){
    unsigned short v = u[(size_t)(t * 16 + j) * 2];
    int e = (v >> 7) & 0xFF;
    c += (e >= 118 && e <= 134);
  }
  atomicAdd(&cnt, c);
  __syncthreads();
  const int isbf = cnt > 2048;
  if (f == 0 && t == 0) flag[0] = isbf ? 1.0f : 0.0f;
  float s = 0.f, ss = 0.f;
  for (int r = t; r < BATCH; r += 256){
    float v = ldin(x, (size_t)r*256 + f, isbf);
    s += v; ss += v*v;
  }
  s  = block_sum(s, sb);
  ss = block_sum(ss, sb);
  if (t == 0){
    float m = s * (1.f/BATCH);
    float is = rsqrtf(ss * (1.f/BATCH) - m*m + BN_EPS_C);
    float A = is * ldin(bnw, f, isbf);
    xnA[f] = A;
    xnB[f] = ldin(bnb, f, isbf) - m*A;
  }
}

// ---- init GEMM K=512 with inline xn affine + xn buffer write --------------
__global__ __launch_bounds__(256)
void gemminit_k(const void* __restrict__ x, const void* __restrict__ bemv,
                const float* __restrict__ xnA, const float* __restrict__ xnB,
                const void* __restrict__ W, float* __restrict__ C,
                float* __restrict__ xn, const float* __restrict__ flg){
  int bid = blockIdx.x, t = threadIdx.x;
  __shared__ float As[32][34];
  __shared__ float Ws[32][34];
  const int isbf = flg[0] != 0.0f;
  const int n0 = (bid & 7) * 32, m0 = (bid >> 3) * 32;
  const int tx = t & 15, ty = t >> 4;
  const int lr = t >> 3, lk = (t & 7) * 4;
  float a00 = 0.f, a01 = 0.f, a10 = 0.f, a11 = 0.f;
  auto lda = [&](int k0) -> float4 {
    int gk = k0 + lk, gr = m0 + lr;
    if (gk < 256){
      float4 xv = ld4(x, (size_t)gr*256 + gk, isbf);
      float4 A4 = *(const float4*)(xnA + gk);
      float4 B4 = *(const float4*)(xnB + gk);
      return make_float4(xv.x*A4.x+B4.x, xv.y*A4.y+B4.y, xv.z*A4.z+B4.z, xv.w*A4.w+B4.w);
    }
    return ld4(bemv, (size_t)gr*256 + (gk - 256), isbf);
  };
  auto ldw = [&](int k0) -> float4 {
    return ld4(W, (size_t)(n0 + lr)*512 + k0 + lk, isbf);
  };
  float4 ra = lda(0), rw = ldw(0);
  for (int c = 0; c < 16; ++c){
    As[lk+0][lr] = ra.x; As[lk+1][lr] = ra.y; As[lk+2][lr] = ra.z; As[lk+3][lr] = ra.w;
    Ws[lk+0][lr] = rw.x; Ws[lk+1][lr] = rw.y; Ws[lk+2][lr] = rw.z; Ws[lk+3][lr] = rw.w;
    __syncthreads();
    float4 na = ra, nw = rw;
    if (c + 1 < 16){ na = lda((c+1) << 5); nw = ldw((c+1) << 5); }
#pragma unroll
    for (int kk = 0; kk < 32; ++kk){
      float2 av = *(const float2*)&As[kk][ty*2];
      float2 wv = *(const float2*)&Ws[kk][tx*2];
      a00 += av.x*wv.x; a01 += av.x*wv.y;
      a10 += av.y*wv.x; a11 += av.y*wv.y;
    }
    __syncthreads();
    ra = na; rw = nw;
  }
  int r0 = m0 + ty*2, c0 = n0 + tx*2;
  float* Cp = C + (size_t)r0*256 + c0;
  Cp[0] = a00; Cp[1] = a01; Cp[256] = a10; Cp[257] = a11;
  // xn buffer (1 float4 per thread; grid 256x256 covers 262144 elems)
  int fi = (bid*256 + t) * 4;
  int col = fi & 255;
  float4 xv = ld4(x, fi, isbf);
  float4 A4 = *(const float4*)(xnA + col);
  float4 B4 = *(const float4*)(xnB + col);
  *(float4*)(xn + fi) = make_float4(xv.x*A4.x+B4.x, xv.y*A4.y+B4.y, xv.z*A4.z+B4.z, xv.w*A4.w+B4.w);
}

// ---- GEMM (BT): C = [A1|A2] @ W^T (r11 verbatim), +drain ------------------
__global__ __launch_bounds__(256)
void gemm_bt_k(const float* __restrict__ A1, const void* __restrict__ A2, int split,
               const void* __restrict__ W, size_t woff, float* __restrict__ C, int K,
               const float* __restrict__ st, float* __restrict__ amap, int dS, int dR0,
               const float* __restrict__ flg){
  int bid = blockIdx.x, t = threadIdx.x;
  if (bid >= 256){ drain_rows(st, amap, dS, dR0 + bid - 256, t); return; }
  __shared__ float As[32][34];
  __shared__ float Ws[32][34];
  const int isbf = flg[0] != 0.0f;
  const int n0 = (bid & 7) * 32, m0 = (bid >> 3) * 32;
  const int tx = t & 15, ty = t >> 4;
  const int lr = t >> 3, lk = (t & 7) * 4;
  const int nc = K >> 5;
  float a00 = 0.f, a01 = 0.f, a10 = 0.f, a11 = 0.f;
  auto lda = [&](int k0) -> float4 {
    int gk = k0 + lk, gr = m0 + lr;
    if (gk < split) return *(const float4*)(A1 + (size_t)gr*split + gk);
    return ld4(A2, (size_t)gr*(K - split) + (gk - split), isbf);
  };
  auto ldw = [&](int k0) -> float4 {
    return ld4(W, woff + (size_t)(n0 + lr)*K + k0 + lk, isbf);
  };
  float4 ra = lda(0), rw = ldw(0);
  for (int c = 0; c < nc; ++c){
    As[lk+0][lr] = ra.x; As[lk+1][lr] = ra.y; As[lk+2][lr] = ra.z; As[lk+3][lr] = ra.w;
    Ws[lk+0][lr] = rw.x; Ws[lk+1][lr] = rw.y; Ws[lk+2][lr] = rw.z; Ws[lk+3][lr] = rw.w;
    __syncthreads();
    float4 na = ra, nw = rw;
    if (c + 1 < nc){ na = lda((c+1) << 5); nw = ldw((c+1) << 5); }
#pragma unroll
    for (int kk = 0; kk < 32; ++kk){
      float2 av = *(const float2*)&As[kk][ty*2];
      float2 wv = *(const float2*)&Ws[kk][tx*2];
      a00 += av.x*wv.x; a01 += av.x*wv.y;
      a10 += av.y*wv.x; a11 += av.y*wv.y;
    }
    __syncthreads();
    ra = na; rw = nw;
  }
  int r0 = m0 + ty*2, c0 = n0 + tx*2;
  float* Cp = C + (size_t)r0*256 + c0;
  Cp[0] = a00; Cp[1] = a01; Cp[256] = a10; Cp[257] = a11;
}

// ---- group-stats + GLU-fused GEMM K=128 (r11 verbatim), +drain ------------
__global__ __launch_bounds__(256)
void glugemm_k(const float* __restrict__ H1, const void* __restrict__ gw,
               const void* __restrict__ gb, size_t goff,
               const void* __restrict__ W, size_t woff, float* __restrict__ C,
               const float* __restrict__ st, float* __restrict__ amap, int dS, int dR0,
               const float* __restrict__ flg){
  int bid = blockIdx.x, t = threadIdx.x;
  if (bid >= 256){ drain_rows(st, amap, dS, dR0 + bid - 256, t); return; }
  __shared__ __align__(16) float sA[256], sB[256];
  __shared__ float As[32][34];
  __shared__ float Ws[32][34];
  const int isbf = flg[0] != 0.0f;
  const int n0 = (bid & 7) * 32, m0 = (bid >> 3) * 32;
  const int g = bid >> 5;
  {
    const float* Hp = H1 + (size_t)g*32768 + t;
    float s = 0.f, ss = 0.f;
#pragma unroll 8
    for (int i = 0; i < 128; ++i){ float v = Hp[(size_t)i*256]; s += v; ss += v*v; }
    float m = s * (1.f/128), is = rsqrtf(ss * (1.f/128) - m*m + BN_EPS_C);
    float wv = ldin(gw, goff + t, isbf), bv = ldin(gb, goff + t, isbf);
    float A = is * wv;
    sA[t] = A; sB[t] = bv - m*A;
  }
  __syncthreads();
  const int tx = t & 15, ty = t >> 4;
  const int lr = t >> 3, lk = (t & 7) * 4;
  float a00 = 0.f, a01 = 0.f, a10 = 0.f, a11 = 0.f;
  auto lda = [&](int k0) -> float4 {
    int gk = k0 + lk, gr = m0 + lr;
    const float* h = H1 + (size_t)gr*256;
    float4 h0 = *(const float4*)(h + gk);
    float4 h1 = *(const float4*)(h + gk + 128);
    float4 A0 = *(const float4*)(sA + gk);
    float4 B0 = *(const float4*)(sB + gk);
    float4 A1 = *(const float4*)(sA + gk + 128);
    float4 B1 = *(const float4*)(sB + gk + 128);
    float4 r;
    r.x = (h0.x*A0.x+B0.x) / (1.f + __expf(-(h1.x*A1.x+B1.x)));
    r.y = (h0.y*A0.y+B0.y) / (1.f + __expf(-(h1.y*A1.y+B1.y)));
    r.z = (h0.z*A0.z+B0.z) / (1.f + __expf(-(h1.z*A1.z+B1.z)));
    r.w = (h0.w*A0.w+B0.w) / (1.f + __expf(-(h1.w*A1.w+B1.w)));
    return r;
  };
  auto ldw = [&](int k0) -> float4 {
    return ld4(W, woff + (size_t)(n0 + lr)*128 + k0 + lk, isbf);
  };
  float4 ra = lda(0), rw = ldw(0);
#pragma unroll 1
  for (int c = 0; c < 4; ++c){
    As[lk+0][lr] = ra.x; As[lk+1][lr] = ra.y; As[lk+2][lr] = ra.z; As[lk+3][lr] = ra.w;
    Ws[lk+0][lr] = rw.x; Ws[lk+1][lr] = rw.y; Ws[lk+2][lr] = rw.z; Ws[lk+3][lr] = rw.w;
    __syncthreads();
    float4 na = ra, nw = rw;
    if (c + 1 < 4){ na = lda((c+1) << 5); nw = ldw((c+1) << 5); }
#pragma unroll
    for (int kk = 0; kk < 32; ++kk){
      float2 av = *(const float2*)&As[kk][ty*2];
      float2 wv = *(const float2*)&Ws[kk][tx*2];
      a00 += av.x*wv.x; a01 += av.x*wv.y;
      a10 += av.y*wv.x; a11 += av.y*wv.y;
    }
    __syncthreads();
    ra = na; rw = nw;
  }
  int r0 = m0 + ty*2, c0 = n0 + tx*2;
  float* Cp = C + (size_t)r0*256 + c0;
  Cp[0] = a00; Cp[1] = a01; Cp[256] = a10; Cp[257] = a11;
}

// ---- fused comb + a-GEMM K=64: Ha = combine(H1,H2) @ afc^T; steps_out -----
__global__ __launch_bounds__(256)
void acomb_k(const float* __restrict__ H1, const float* __restrict__ H2,
             const void* __restrict__ p0w, const void* __restrict__ p0b, size_t off0,
             const void* __restrict__ p1w, const void* __restrict__ p1b, size_t off1,
             const void* __restrict__ afc, size_t aoff, float* __restrict__ Ha,
             float* __restrict__ steps_prev,
             const float* __restrict__ st, float* __restrict__ amap, int dS, int dR0,
             const float* __restrict__ flg){
  int bid = blockIdx.x, t = threadIdx.x;
  if (bid >= 256){ drain_rows(st, amap, dS, dR0 + bid - 256, t); return; }
  __shared__ __align__(16) float sA0[256], sB0[256], sA1[256], sB1[256];
  __shared__ float As[32][34];
  __shared__ float Ws[32][34];
  const int isbf = flg[0] != 0.0f;
  const int n0 = (bid & 7) * 32, m0 = (bid >> 3) * 32;
  const int g = m0 >> 7;
  {
    const float* h1p = H1 + (size_t)g*32768 + t;
    const float* h2p = H2 + (size_t)g*32768 + t;
    float s0 = 0.f, ss0 = 0.f, s1 = 0.f, ss1 = 0.f;
#pragma unroll 8
    for (int i = 0; i < 128; ++i){
      float v = h1p[(size_t)i*256]; s0 += v; ss0 += v*v;
      float w = h2p[(size_t)i*256]; s1 += w; ss1 += w*w;
    }
    float m = s0 * (1.f/128), is = rsqrtf(ss0 * (1.f/128) - m*m + BN_EPS_C);
    float A = is * ldin(p0w, off0 + t, isbf);
    sA0[t] = A; sB0[t] = ldin(p0b, off0 + t, isbf) - m*A;
    m = s1 * (1.f/128); is = rsqrtf(ss1 * (1.f/128) - m*m + BN_EPS_C);
    A = is * ldin(p1w, off1 + t, isbf);
    sA1[t] = A; sB1[t] = ldin(p1b, off1 + t, isbf) - m*A;
  }
  __syncthreads();
  const int tx = t & 15, ty = t >> 4;
  const int lr = t >> 3, lk = (t & 7) * 4;
  float a00 = 0.f, a01 = 0.f, a10 = 0.f, a11 = 0.f;
  auto lda = [&](int k0) -> float4 {
    int gk = k0 + lk, gr = m0 + lr;      // att col gk -> combine col j=64+gk
    const float* h1 = H1 + (size_t)gr*256;
    const float* h2 = H2 + (size_t)gr*256;
    float4 a0 = *(const float4*)(h1 + 64 + gk);
    float4 a1 = *(const float4*)(h1 + 192 + gk);
    float4 b0 = *(const float4*)(h2 + 64 + gk);
    float4 b1 = *(const float4*)(h2 + 192 + gk);
    float4 c0 = *(const float4*)(sA0 + 64 + gk),  d0 = *(const float4*)(sB0 + 64 + gk);
    float4 c1 = *(const float4*)(sA0 + 192 + gk), d1 = *(const float4*)(sB0 + 192 + gk);
    float4 e0 = *(const float4*)(sA1 + 64 + gk),  f0 = *(const float4*)(sB1 + 64 + gk);
    float4 e1 = *(const float4*)(sA1 + 192 + gk), f1 = *(const float4*)(sB1 + 192 + gk);
    float4 r;
    r.x = ((a0.x*c0.x+d0.x)/(1.f+__expf(-(a1.x*c1.x+d1.x)))
         + (b0.x*e0.x+f0.x)/(1.f+__expf(-(b1.x*e1.x+f1.x)))) * SQRT_HALF_C;
    r.y = ((a0.y*c0.y+d0.y)/(1.f+__expf(-(a1.y*c1.y+d1.y)))
         + (b0.y*e0.y+f0.y)/(1.f+__expf(-(b1.y*e1.y+f1.y)))) * SQRT_HALF_C;
    r.z = ((a0.z*c0.z+d0.z)/(1.f+__expf(-(a1.z*c1.z+d1.z)))
         + (b0.z*e0.z+f0.z)/(1.f+__expf(-(b1.z*e1.z+f1.z)))) * SQRT_HALF_C;
    r.w = ((a0.w*c0.w+d0.w)/(1.f+__expf(-(a1.w*c1.w+d1.w)))
         + (b0.w*e0.w+f0.w)/(1.f+__expf(-(b1.w*e1.w+f1.w)))) * SQRT_HALF_C;
    return r;
  };
  auto ldw = [&](int k0) -> float4 {
    return ld4(afc, aoff + (size_t)(n0 + lr)*64 + k0 + lk, isbf);
  };
  float4 ra = lda(0), rw = ldw(0);
#pragma unroll 1
  for (int c = 0; c < 2; ++c){
    As[lk+0][lr] = ra.x; As[lk+1][lr] = ra.y; As[lk+2][lr] = ra.z; As[lk+3][lr] = ra.w;
    Ws[lk+0][lr] = rw.x; Ws[lk+1][lr] = rw.y; Ws[lk+2][lr] = rw.z; Ws[lk+3][lr] = rw.w;
    __syncthreads();
    float4 na = ra, nw = rw;
    if (c + 1 < 2){ na = lda(32); nw = ldw(32); }
#pragma unroll
    for (int kk = 0; kk < 32; ++kk){
      float2 av = *(const float2*)&As[kk][ty*2];
      float2 wv = *(const float2*)&Ws[kk][tx*2];
      a00 += av.x*wv.x; a01 += av.x*wv.y;
      a10 += av.y*wv.x; a11 += av.y*wv.y;
    }
    __syncthreads();
    ra = na; rw = nw;
  }
  int r0 = m0 + ty*2, c0 = n0 + tx*2;
  float* Cp = Ha + (size_t)r0*256 + c0;
  Cp[0] = a00; Cp[1] = a01; Cp[256] = a10; Cp[257] = a11;
  // steps_out[s-1] for rows m0..m0+31 by n0==0 blocks (cols j<64)
  if (steps_prev && (bid & 7) == 0){
#pragma unroll
    for (int ii = 0; ii < 8; ++ii){
      int idx = t + ii*256;
      int r = m0 + (idx >> 6), j = idx & 63;
      float h0 = H1[(size_t)r*256 + j], h1 = H1[(size_t)r*256 + j + 128];
      float u0 = h0 * sA0[j]     + sB0[j];
      float u1 = h1 * sA0[j+128] + sB0[j+128];
      float g0 = u0 / (1.f + __expf(-u1));
      float v0 = H2[(size_t)r*256 + j]     * sA1[j]     + sB1[j];
      float v1 = H2[(size_t)r*256 + j+128] * sA1[j+128] + sB1[j+128];
      float g1 = v0 / (1.f + __expf(-v1));
      float f = (g0 + g1) * SQRT_HALF_C;
      steps_prev[(size_t)r*64 + j] = f > 0.f ? f : 0.01f*f;
    }
  }
}

// ---- fused stats + sparsemax + prior + loss + sparse-xm + attention -------
__global__ __launch_bounds__(256)
void cd_k(const float* __restrict__ Ha, const void* __restrict__ abnw,
          const void* __restrict__ abnb, size_t aoff2, float* __restrict__ prior,
          const float* __restrict__ xn, const void* __restrict__ gmat,
          float* __restrict__ y, float* __restrict__ lrow, int first,
          const void* __restrict__ siw, const void* __restrict__ sib,
          const void* __restrict__ sow, const void* __restrict__ sob, int s,
          float* __restrict__ stt, float* __restrict__ amap, int dS, int dR0,
          const float* __restrict__ flg){
  int bid = blockIdx.x, t = threadIdx.x;
  if (bid >= 1024){ drain_rows(stt, amap, dS, dR0 + bid - 1024, t); return; }
  __shared__ __align__(16) float zt[256], prt[256], tabs[256];
  __shared__ __align__(16) float ks[256], vs[256];
  __shared__ float r1[4], r2[4];
  __shared__ unsigned int msk2[2];
  const int isbf = flg[0] != 0.0f;
  const int b = bid, g = b >> 7;
  // group stats for col t over Ha
  float AA, BB;
  {
    const float* Hp = Ha + (size_t)g*32768 + t;
    float s0 = 0.f, ss0 = 0.f;
#pragma unroll 8
    for (int i = 0; i < 128; ++i){ float v = Hp[(size_t)i*256]; s0 += v; ss0 += v*v; }
    float m = s0 * (1.f/128), is = rsqrtf(ss0 * (1.f/128) - m*m + BN_EPS_C);
    AA = is * ldin(abnw, aoff2 + t, isbf);
    BB = ldin(abnb, aoff2 + t, isbf) - m*AA;
  }
  float hv = Ha[(size_t)b*256 + t];
  float pr = first ? 1.f : prior[(size_t)b*256 + t];
  zt[t] = (hv*AA + BB) * pr;
  prt[t] = pr;
  __syncthreads();
  // wave-redundant barrier-free bisection (each wave solves the same row)
  int lane = t & 63, wv = t >> 6;
  float4 z4 = *(const float4*)&zt[lane*4];
  float zm = wmaxr(fmaxf(fmaxf(z4.x, z4.y), fmaxf(z4.z, z4.w)));
  float lo = zm - 1.f, hi = zm;
#pragma unroll 1
  for (int it = 0; it < 30; ++it){
    float mid = 0.5f * (lo + hi);
    float sv = fmaxf(z4.x - mid, 0.f) + fmaxf(z4.y - mid, 0.f)
             + fmaxf(z4.z - mid, 0.f) + fmaxf(z4.w - mid, 0.f);
    sv = wsum(sv);
    if (sv >= 1.f) lo = mid; else hi = mid;
  }
  float tau = 0.5f * (lo + hi);
  float p0 = fmaxf(z4.x - tau, 0.f), p1 = fmaxf(z4.y - tau, 0.f);
  float p2 = fmaxf(z4.z - tau, 0.f), p3 = fmaxf(z4.w - tau, 0.f);
  if (wv == 0){
    float4 pr4 = *(const float4*)&prt[lane*4];
    *(float4*)&tabs[lane*4] = make_float4(p0, p1, p2, p3);
    *(float4*)(prior + (size_t)b*256 + lane*4) =
        make_float4(pr4.x*(GAMMA_C-p0), pr4.y*(GAMMA_C-p1),
                    pr4.z*(GAMMA_C-p2), pr4.w*(GAMMA_C-p3));
    float ls = p0*__logf(p0 + 1e-15f) + p1*__logf(p1 + 1e-15f)
             + p2*__logf(p2 + 1e-15f) + p3*__logf(p3 + 1e-15f);
    ls = wsum(ls);
    if (lane == 0) lrow[b] = ls;
    bool nz = (p0 > 0.f) | (p1 > 0.f) | (p2 > 0.f) | (p3 > 0.f);
    unsigned long long bm = __ballot(nz);
    if (lane == 0){ msk2[0] = (unsigned int)bm; msk2[1] = (unsigned int)(bm >> 32); }
  }
  __syncthreads();
  unsigned long long M = msk2[0] | ((unsigned long long)msk2[1] << 32);
  // sparse xm for col t
  float acc = 0.f;
#pragma unroll 1
  for (int c = 0; c < 64; ++c){
    if ((M >> c) & 1){
      int k = c * 4;
      float g0 = ldin(gmat, (size_t)(k+0)*256 + t, isbf);
      float g1 = ldin(gmat, (size_t)(k+1)*256 + t, isbf);
      float g2 = ldin(gmat, (size_t)(k+2)*256 + t, isbf);
      float g3 = ldin(gmat, (size_t)(k+3)*256 + t, isbf);
      float4 tv = *(const float4*)&tabs[k];
      acc += tv.x*g0 + tv.y*g1 + tv.z*g2 + tv.w*g3;
    }
  }
  float xv = acc * xn[(size_t)b*256 + t];
  // attention (r11 attnA body)
  float w0 = ldin(siw, s*3+0, isbf), w1 = ldin(siw, s*3+1, isbf), w2 = ldin(siw, s*3+2, isbf);
  float b0 = ldin(sib, s*3+0, isbf), b1 = ldin(sib, s*3+1, isbf), b2 = ldin(sib, s*3+2, isbf);
  float ow = ldin(sow, s, isbf), ob = ldin(sob, s, isbf);
  float q = xv*w0 + b0, k = xv*w1 + b1, v = xv*w2 + b2;
  ks[t] = k; vs[t] = v;
  float km = wmaxr(k), kn = wminr(k);
  if (lane == 0){ r1[wv] = km; r2[wv] = kn; }
  __syncthreads();
  float kmax = fmaxf(fmaxf(r1[0], r1[1]), fmaxf(r1[2], r1[3]));
  float kmin = fminf(fminf(r2[0], r2[1]), fminf(r2[2], r2[3]));
  float mi = (q >= 0.f) ? q*kmax : q*kmin;
  float Z = 0.f, Y = 0.f;
#pragma unroll 8
  for (int j = 0; j < 256; j += 4){
    float4 k4 = *(const float4*)&ks[j];
    float4 v4 = *(const float4*)&vs[j];
    float e0 = __expf(q*k4.x - mi), e1 = __expf(q*k4.y - mi);
    float e2 = __expf(q*k4.z - mi), e3 = __expf(q*k4.w - mi);
    Z += (e0 + e1) + (e2 + e3);
    Y += (e0*v4.x + e1*v4.y) + (e2*v4.z + e3*v4.w);
  }
  float rz = 1.f / Z;
  y[(size_t)b*256 + t] = Y*rz*ow + ob;
  size_t sb = ((size_t)s*BATCH + b)*256 + t;
  stt[sb]               = q;
  stt[ST_STRIDE + sb]   = k;
  stt[2*ST_STRIDE + sb] = mi;
  stt[3*ST_STRIDE + sb] = rz;
}

// ---- final: mloss + steps_out[2] + tail drains ----------------------------
__global__ __launch_bounds__(256)
void fin_k(const float* __restrict__ lrow, float* __restrict__ outp,
           const float* __restrict__ H1, const void* __restrict__ pw0,
           const void* __restrict__ pb0, size_t off0,
           const float* __restrict__ H2, const void* __restrict__ pw1,
           const void* __restrict__ pb1, size_t off1,
           float* __restrict__ steps2,
           const float* __restrict__ st, float* __restrict__ amap,
           const float* __restrict__ flg){
  int bid = blockIdx.x, t = threadIdx.x;
  if (bid >= 257){ drain_rows(st, amap, 2, 512 + bid - 257, t); return; }
  if (bid == 0){
    __shared__ float sb[256];
    float v = 0.f;
    for (int i = t; i < N_STEPS*BATCH; i += 256) v += lrow[i];
    v = block_sum(v, sb);
    if (t == 0) outp[0] = v * (1.f/(N_STEPS*(float)BATCH));
    return;
  }
  __shared__ __align__(16) float sA0[256], sB0[256], sA1[256], sB1[256];
  const int isbf = flg[0] != 0.0f;
  int sbk = bid - 1;
  int g = sbk >> 5;
  {
    const float* h1p = H1 + (size_t)g*32768 + t;
    const float* h2p = H2 + (size_t)g*32768 + t;
    float s0 = 0.f, ss0 = 0.f, s1 = 0.f, ss1 = 0.f;
#pragma unroll 8
    for (int i = 0; i < 128; ++i){
      float v = h1p[(size_t)i*256]; s0 += v; ss0 += v*v;
      float w = h2p[(size_t)i*256]; s1 += w; ss1 += w*w;
    }
    float m = s0 * (1.f/128), is = rsqrtf(ss0 * (1.f/128) - m*m + BN_EPS_C);
    float A = is * ldin(pw0, off0 + t, isbf);
    sA0[t] = A; sB0[t] = ldin(pb0, off0 + t, isbf) - m*A;
    m = s1 * (1.f/128); is = rsqrtf(ss1 * (1.f/128) - m*m + BN_EPS_C);
    A = is * ldin(pw1, off1 + t, isbf);
    sA1[t] = A; sB1[t] = ldin(pb1, off1 + t, isbf) - m*A;
  }
  __syncthreads();
  int r = sbk*4 + (t >> 6), j = t & 63;
  float h0 = H1[(size_t)r*256 + j], h1 = H1[(size_t)r*256 + j + 128];
  float u0 = h0 * sA0[j]     + sB0[j];
  float u1 = h1 * sA0[j+128] + sB0[j+128];
  float g0 = u0 / (1.f + __expf(-u1));
  float v0 = H2[(size_t)r*256 + j]     * sA1[j]     + sB1[j];
  float v1 = H2[(size_t)r*256 + j+128] * sA1[j+128] + sB1[j+128];
  float g1 = v0 / (1.f + __expf(-v1));
  float f = (g0 + g1) * SQRT_HALF_C;
  steps2[(size_t)r*64 + j] = f > 0.f ? f : 0.01f*f;
}

extern "C" void kernel_launch(void* const* d_in, const int* in_sizes, int n_in,
                              void* d_out, int out_size, void* d_ws, size_t ws_size,
                              hipStream_t stream){
  const void* x         = d_in[0];
  const void* bemv      = d_in[1];
  const void* gmat      = d_in[2];
  const void* bn_w      = d_in[3];
  const void* bn_b      = d_in[4];
  const void* init_fc0  = d_in[5];
  const void* init_bnw0 = d_in[6];
  const void* init_bnb0 = d_in[7];
  const void* init_fc1  = d_in[8];
  const void* init_bnw1 = d_in[9];
  const void* init_bnb1 = d_in[10];
  const void* step_fc0  = d_in[11];
  const void* step_bnw0 = d_in[12];
  const void* step_bnb0 = d_in[13];
  const void* step_fc1  = d_in[14];
  const void* step_bnw1 = d_in[15];
  const void* step_bnb1 = d_in[16];
  const void* att_fc    = d_in[17];
  const void* att_bnw   = d_in[18];
  const void* att_bnb   = d_in[19];
  const void* sa_in_w   = d_in[20];
  const void* sa_in_b   = d_in[21];
  const void* sa_out_w  = d_in[22];
  const void* sa_out_b  = d_in[23];

  float* out       = (float*)d_out;
  float* steps_out = out;                               // 3*1024*64
  float* mloss_out = out + 196608;                      // 1
  float* amaps     = out + 196609;                      // 3*1024*256*256

  float* w     = (float*)d_ws;
  float* flag  = w;                   // [0,16)
  float* xnA   = w + 16;              // 256
  float* xnB   = w + 272;             // 256
  float* lrow  = w + 528;             // 3072
  float* xn    = w + 4096;            // 262144
  float* H1    = xn + 262144;
  float* H2    = H1 + 262144;
  float* Ha    = H2 + 262144;
  float* prior = Ha + 262144;
  float* y     = prior + 262144;
  float* st    = y + 262144;          // 4 * ST_STRIDE

  bnstatsD_k<<<256, 256, 0, stream>>>(x, bn_w, bn_b, xnA, xnB, flag);
  gemminit_k<<<256, 256, 0, stream>>>(x, bemv, xnA, xnB, init_fc0, H1, xn, flag);
  glugemm_k<<<256, 256, 0, stream>>>(H1, init_bnw0, init_bnb0, 0, init_fc1, 0, H2,
                                     st, amaps, 0, 0, flag);

  for (int s = 0; s < N_STEPS; ++s){
    int pd = s - 1;
    int dn = (s >= 1) ? 256 : 0;
    const void *p0w, *p0b, *p1w, *p1b; size_t off0, off1;
    if (s == 0){ p0w = init_bnw0; p0b = init_bnb0; off0 = 0;
                 p1w = init_bnw1; p1b = init_bnb1; off1 = 0; }
    else       { p0w = step_bnw0; p0b = step_bnb0; off0 = (size_t)(s-1)*256;
                 p1w = step_bnw1; p1b = step_bnb1; off1 = (size_t)(s-1)*256; }
    // fused comb + a-GEMM -> Ha; steps_out[s-1]; drains pd rows [512..768)
    acomb_k<<<256 + dn, 256, 0, stream>>>(H1, H2, p0w, p0b, off0, p1w, p1b, off1,
                                          att_fc, (size_t)s*16384, Ha,
                                          s > 0 ? steps_out + (size_t)(s-1)*65536 : nullptr,
                                          st, amaps, pd, 512, flag);
    // fused stats+sparsemax+xm+attention -> y + state; drains pd rows [768..1024)
    cd_k<<<1024 + dn, 256, 0, stream>>>(Ha, att_bnw, att_bnb, (size_t)s*256, prior,
                                        xn, gmat, y, lrow + s*1024, s == 0,
                                        sa_in_w, sa_in_b, sa_out_w, sa_out_b, s,
                                        st, amaps, pd, 768, flag);
    // step GEMM K=512 -> H1; drains s rows [0..256)
    gemm_bt_k<<<512, 256, 0, stream>>>(y, bemv, 256, step_fc0, (size_t)s*131072, H1, 512,
                                       st, amaps, s, 0, flag);
    // GLU GEMM K=128 -> H2; drains s rows [256..512)
    glugemm_k<<<512, 256, 0, stream>>>(H1, step_bnw0, step_bnb0, (size_t)s*256,
                                       step_fc1, (size_t)s*32768, H2,
                                       st, amaps, s, 256, flag);
  }
  // mloss + steps_out[2] + drain s=2 rows [512..1024)
  fin_k<<<769, 256, 0, stream>>>(lrow, mloss_out,
                                 H1, step_bnw0, step_bnb0, (size_t)2*256,
                                 H2, step_bnw1, step_bnb1, (size_t)2*256,
                                 steps_out + (size_t)2*65536,
                                 st, amaps, flag);
}